// Round 13
// baseline (226.713 us; speedup 1.0000x reference)
//
#include <hip/hip_runtime.h>
#include <hip/hip_bf16.h>
#include <math.h>

#define N_K 5292
#define N_KP 5376     // N_K padded to multiple of 64 for permuted V layout
#define N_Q 1344
#define NH_KD 128
#define LOG2E 1.4426950408889634f
#define MSTAT 16.0f   // static softmax shift (log2 domain), in QK MFMA C-operand
#define BTM_H 20750   // 125*166 mirrored bias entries per head

typedef float f32x4 __attribute__((ext_vector_type(4)));
typedef short short8 __attribute__((ext_vector_type(8)));

__device__ __forceinline__ float fexp2(float x) {
#if __has_builtin(__builtin_amdgcn_exp2f)
    return __builtin_amdgcn_exp2f(x);
#else
    return exp2f(x);
#endif
}

// packed f32x2 -> bf16x2 (v_cvt_pk_bf16_f32); a in low 16 bits
__device__ __forceinline__ unsigned pk_bf16(float a, float b) {
    union { __hip_bfloat162 h; unsigned u; } c;
    c.h = __float22bfloat162_rn(make_float2(a, b));
    return c.u;
}
__device__ __forceinline__ unsigned short f2bf(float a) {
    return (unsigned short)pk_bf16(a, 0.f);
}

// ---- GEMM tile body, A fp32 source (inline bf16 cvt), W fp32 source ----
__device__ __forceinline__ void gemm_body_f32(
    const float* __restrict__ A, const float* __restrict__ W,
    long asrc, int nrow,
    unsigned short (*As)[40], unsigned short (*Bs)[40], f32x4 acc[4])
{
    const int t = threadIdx.x;
    const int w = t >> 6, lane = t & 63, g = lane >> 4, ln = lane & 15;
    const int srow = t >> 2;
    const int sc8 = (t & 3) * 8;

    for (int k0 = 0; k0 < 256; k0 += 32) {
        uint4 a = make_uint4(0, 0, 0, 0);
        if (asrc >= 0) {
            float4 a0 = *(const float4*)(A + asrc * 256 + k0 + sc8);
            float4 a1 = *(const float4*)(A + asrc * 256 + k0 + sc8 + 4);
            a = make_uint4(pk_bf16(a0.x, a0.y), pk_bf16(a0.z, a0.w),
                           pk_bf16(a1.x, a1.y), pk_bf16(a1.z, a1.w));
        }
        float4 b0 = *(const float4*)(W + (size_t)nrow * 256 + k0 + sc8);
        float4 b1 = *(const float4*)(W + (size_t)nrow * 256 + k0 + sc8 + 4);
        uint4 b = make_uint4(pk_bf16(b0.x, b0.y), pk_bf16(b0.z, b0.w),
                             pk_bf16(b1.x, b1.y), pk_bf16(b1.z, b1.w));

        __syncthreads();
        *(uint4*)&As[srow][sc8] = a;
        *(uint4*)&Bs[srow][sc8] = b;
        __syncthreads();

        short8 ah = *(const short8*)&As[w * 16 + ln][g * 8];
        #pragma unroll
        for (int nt = 0; nt < 4; ++nt) {
            short8 bh = *(const short8*)&Bs[nt * 16 + ln][g * 8];
            acc[nt] = __builtin_amdgcn_mfma_f32_16x16x32_bf16(ah, bh, acc[nt], 0, 0, 0);
        }
    }
}

// ---- GEMM tile body, A bf16 source, W fp32 source ----
__device__ __forceinline__ void gemm_body_bf16(
    const unsigned short* __restrict__ A, const float* __restrict__ W,
    long asrc, int nrow,
    unsigned short (*As)[40], unsigned short (*Bs)[40], f32x4 acc[4])
{
    const int t = threadIdx.x;
    const int w = t >> 6, lane = t & 63, g = lane >> 4, ln = lane & 15;
    const int srow = t >> 2;
    const int sc8 = (t & 3) * 8;

    for (int k0 = 0; k0 < 256; k0 += 32) {
        uint4 a = *(const uint4*)(A + asrc * 256 + k0 + sc8);
        float4 b0 = *(const float4*)(W + (size_t)nrow * 256 + k0 + sc8);
        float4 b1 = *(const float4*)(W + (size_t)nrow * 256 + k0 + sc8 + 4);
        uint4 b = make_uint4(pk_bf16(b0.x, b0.y), pk_bf16(b0.z, b0.w),
                             pk_bf16(b1.x, b1.y), pk_bf16(b1.z, b1.w));

        __syncthreads();
        *(uint4*)&As[srow][sc8] = a;
        *(uint4*)&Bs[srow][sc8] = b;
        __syncthreads();

        short8 ah = *(const short8*)&As[w * 16 + ln][g * 8];
        #pragma unroll
        for (int nt = 0; nt < 4; ++nt) {
            short8 bh = *(const short8*)&Bs[nt * 16 + ln][g * 8];
            acc[nt] = __builtin_amdgcn_mfma_f32_16x16x32_bf16(ah, bh, acc[nt], 0, 0, 0);
        }
    }
}

// ---- fused column stats (sum/sumsq of this block's 64 rows) ----
__device__ __forceinline__ void gemm_stats(f32x4 acc[4], float* __restrict__ sums,
                                           int n0, int Ncols, float* scratch)
{
    const int t = threadIdx.x;
    const int w = t >> 6, lane = t & 63, g = lane >> 4, ln = lane & 15;
    float s4[4], q4[4];
    #pragma unroll
    for (int nt = 0; nt < 4; ++nt) {
        float s = acc[nt][0] + acc[nt][1] + acc[nt][2] + acc[nt][3];
        float q = fmaf(acc[nt][0], acc[nt][0], fmaf(acc[nt][1], acc[nt][1],
                  fmaf(acc[nt][2], acc[nt][2], acc[nt][3] * acc[nt][3])));
        s += __shfl_xor(s, 16); s += __shfl_xor(s, 32);
        q += __shfl_xor(q, 16); q += __shfl_xor(q, 32);
        s4[nt] = s; q4[nt] = q;
    }
    __syncthreads();
    float* st_s = scratch;
    float* st_q = scratch + 256;
    if (g == 0) {
        #pragma unroll
        for (int nt = 0; nt < 4; ++nt) {
            st_s[(w * 4 + nt) * 16 + ln] = s4[nt];
            st_q[(w * 4 + nt) * 16 + ln] = q4[nt];
        }
    }
    __syncthreads();
    if (t < 64) {
        int nt = t >> 4, c = t & 15;
        float a = 0.f, b2 = 0.f;
        #pragma unroll
        for (int ww = 0; ww < 4; ++ww) {
            a  += st_s[(ww * 4 + nt) * 16 + c];
            b2 += st_q[(ww * 4 + nt) * 16 + c];
        }
        atomicAdd(&sums[n0 + nt * 16 + c], a);
        atomicAdd(&sums[Ncols + n0 + nt * 16 + c], b2);
    }
}

// ---- kv + q GEMMs + folded prep (race-free Vpt tail zero, mirrored bias build) ----
// kv writes raw bf16 K (per-head) and V (per-head, transposed + slot-permuted).
// Tail zeroing touches ONLY slots whose key >= N_K (never written by the GEMM),
// so the fused launch has no write-write race regardless of block order.
__global__ __launch_bounds__(256) void gemm_qkv(
    const float* __restrict__ X, const float* __restrict__ kv_w, const float* __restrict__ q_w,
    const float* __restrict__ bias_table, const int* __restrict__ bias_idxs, int n_off,
    unsigned short* __restrict__ Kp, unsigned short* __restrict__ Vpt,
    unsigned short* __restrict__ btm_g,
    float* __restrict__ q_y, float* __restrict__ sums_kv, float* __restrict__ sums_q)
{
    __shared__ unsigned short As[64][40], Bs[64][40];
    const int t = threadIdx.x;
    const int w = t >> 6, lane = t & 63, g = lane >> 4, ln = lane & 15;
    const int srow = t >> 2;
    int id = blockIdx.x;

    if (id >= 1104) {
        id -= 1104;
        if (id < 168) {           // zero the 84 never-written Vpt slots per row
            int i = id * 256 + t; // 512 rows x 84 slots = 43008 (exact)
            int row = i / 84, j = i - row * 84;
            int slot;
            if (j < 20) {         // group [5248,5312): slots of keys 5292..5311
                int kap = 44 + j;
                slot = 5248 + (((kap & 15) << 2) | (kap >> 4));
            } else {              // group [5312,5376): fully padding
                slot = 5312 + (j - 20);
            }
            Vpt[(size_t)row * N_KP + slot] = 0;
        } else {                  // build mirrored bias: btm_g[h][dr+62][dc+83]
            int i = (id - 168) * 256 + t;
            if (i < 8 * BTM_H) {
                int h = i / BTM_H, r = i - h * BTM_H;
                int dri = r / 166, dci = r - dri * 166;
                int dr = dri - 62; dr = dr < 0 ? -dr : dr;
                int dc = dci - 83; dc = dc < 0 ? -dc : dc;
                btm_g[i] = f2bf(bias_table[h * n_off + bias_idxs[dr * 84 + dc]] * LOG2E);
            }
        }
        return;
    }

    f32x4 acc[4];
    #pragma unroll
    for (int nt = 0; nt < 4; ++nt) acc[nt] = (f32x4){0.f, 0.f, 0.f, 0.f};

    if (id < 1008) {            // kv: mtiles=166, nblk=6
        const int xcd = id & 7, id8 = id >> 3;
        const int my = xcd + (id8 / 6) * 8, ny = id8 % 6;
        if (my >= 166) return;
        const int m0 = my * 64, n0 = ny * 64;
        int mrow = m0 + srow;
        long asrc = (mrow < 10584) ? mrow : -1;
        gemm_body_f32(X, kv_w, asrc, n0 + srow, As, Bs, acc);

        #pragma unroll
        for (int nt = 0; nt < 4; ++nt) {
            int c = n0 + nt * 16 + ln;
            int hh = c / 48, cc = c - 48 * hh;
            #pragma unroll
            for (int reg = 0; reg < 4; ++reg) {
                int mr = m0 + w * 16 + g * 4 + reg;
                if (mr < 10584) {
                    int bb = mr >= N_K;
                    int key = mr - bb * N_K;
                    unsigned short v16 = f2bf(acc[nt][reg]);
                    if (cc < 16) {
                        Kp[((size_t)(bb * 8 + hh) * N_K + key) * 16 + cc] = v16;
                    } else {
                        int kap = key & 63;
                        int keyp = (key & ~63) | (((kap & 15) << 2) | (kap >> 4));
                        Vpt[((size_t)(bb * 8 + hh) * 32 + cc - 16) * N_KP + keyp] = v16;
                    }
                }
            }
        }
        gemm_stats(acc, sums_kv, n0, 384, (float*)&As[0][0]);
    } else {                    // q: mtiles=42, nblk=2 (strided subsample rows)
        id -= 1008;
        const int xcd = id & 7, id8 = id >> 3;
        const int my = xcd + (id8 / 2) * 8, ny = id8 % 2;
        if (my >= 42) return;
        const int m0 = my * 64, n0 = ny * 64;
        int mrow = m0 + srow;
        int bb = mrow / N_Q;
        int i = mrow - bb * N_Q;
        long asrc = (long)(bb * N_K + (i / 42) * 168 + (i % 42) * 2);
        gemm_body_f32(X, q_w, asrc, n0 + srow, As, Bs, acc);

        #pragma unroll
        for (int nt = 0; nt < 4; ++nt)
            #pragma unroll
            for (int reg = 0; reg < 4; ++reg) {
                int mr = m0 + w * 16 + g * 4 + reg;
                q_y[(size_t)mr * 128 + n0 + nt * 16 + ln] = acc[nt][reg];
            }
        gemm_stats(acc, sums_q, n0, 128, (float*)&As[0][0]);
    }
}

// ---- proj GEMM (A bf16 attn_o, W fp32) ----
__global__ __launch_bounds__(256) void gemm_proj(
    const unsigned short* __restrict__ Ap, const float* __restrict__ Wp,
    float* __restrict__ Y, float* __restrict__ sums)
{
    __shared__ unsigned short As[64][40], Bs[64][40];
    const int t = threadIdx.x;
    const int w = t >> 6, lane = t & 63, g = lane >> 4, ln = lane & 15;
    const int id = blockIdx.x;
    const int xcd = id & 7, id8 = id >> 3;
    const int my = xcd + (id8 / 8) * 8, ny = id8 % 8;
    if (my >= 42) return;
    const int m0 = my * 64, n0 = ny * 64;

    f32x4 acc[4];
    #pragma unroll
    for (int nt = 0; nt < 4; ++nt) acc[nt] = (f32x4){0.f, 0.f, 0.f, 0.f};
    gemm_body_bf16(Ap, Wp, m0 + (t >> 2), n0 + (t >> 2), As, Bs, acc);

    #pragma unroll
    for (int nt = 0; nt < 4; ++nt)
        #pragma unroll
        for (int reg = 0; reg < 4; ++reg) {
            int mr = m0 + w * 16 + g * 4 + reg;
            Y[(size_t)mr * 512 + n0 + nt * 16 + ln] = acc[nt][reg];
        }
    gemm_stats(acc, sums, n0, 512, (float*)&As[0][0]);
}

// ======== flash attention, intra-block ks-split, no K/V LDS staging ========
// grid 1344: h=id&7 (XCD pin), b=(id>>3)&1, qt=id>>4 (16-q tiles).
// Wave w handles K-quarter w for the SAME 16 q rows; combine via LDS barrier.
// B-operands (K, permuted-V) load direct from L2-resident global, 2x-unrolled
// register double buffer. Bias from pre-mirrored global table window in LDS.

struct Frags { short8 kf[4]; short8 v0[2]; short8 v1[2]; };

__device__ __forceinline__ void load_frags(
    Frags& f, int k0, int lane, int g, int ln,
    const unsigned short* __restrict__ kp_base,
    const unsigned short* __restrict__ vrow0,
    const unsigned short* __restrict__ vrow1)
{
    #pragma unroll
    for (int st = 0; st < 4; ++st) {
        int kg = k0 + st * 16 + ln;
        kg = kg > N_K - 1 ? N_K - 1 : kg;
        f.kf[st] = (lane < 32) ? *(const short8*)(kp_base + (size_t)kg * 16 + g * 8)
                               : (short8)0;
    }
    #pragma unroll
    for (int kt = 0; kt < 2; ++kt) {
        f.v0[kt] = *(const short8*)(vrow0 + k0 + kt * 32 + g * 8);
        f.v1[kt] = *(const short8*)(vrow1 + k0 + kt * 32 + g * 8);
    }
}

__device__ __forceinline__ void do_tile(
    const Frags& f, int k0, bool mask, int kend_mask,
    const short8& qfrag, const int base[4], int off[4], int kcc[4],
    const unsigned short* __restrict__ btm_s, int mx,
    int w, int g, int ln, unsigned short (*P_s)[16][72],
    float l[4], f32x4& acc0, f32x4& acc1)
{
    const f32x4 minit = {-MSTAT, -MSTAT, -MSTAT, -MSTAT};
    f32x4 sf[4];
    #pragma unroll
    for (int st = 0; st < 4; ++st)
        sf[st] = __builtin_amdgcn_mfma_f32_16x16x32_bf16(qfrag, f.kf[st], minit, 0, 0, 0);

    float pv[4][4];
    #pragma unroll
    for (int st = 0; st < 4; ++st) {
        #pragma unroll
        for (int reg = 0; reg < 4; ++reg) {
            int idx = base[reg] + off[st];
            idx = idx < 0 ? 0 : idx;
            idx = idx > mx ? mx : idx;
            float bias = __uint_as_float(((unsigned)btm_s[idx]) << 16);
            pv[st][reg] = fexp2(sf[st][reg] + bias);
        }
    }
    if (mask) {
        #pragma unroll
        for (int st = 0; st < 4; ++st) {
            bool bad = (k0 + st * 16 + ln) >= kend_mask;
            #pragma unroll
            for (int reg = 0; reg < 4; ++reg)
                pv[st][reg] = bad ? 0.f : pv[st][reg];
        }
    }

    #pragma unroll
    for (int reg = 0; reg < 4; ++reg) {
        l[reg] += (pv[0][reg] + pv[1][reg]) + (pv[2][reg] + pv[3][reg]);
        uint2 pw = make_uint2(pk_bf16(pv[0][reg], pv[1][reg]),
                              pk_bf16(pv[2][reg], pv[3][reg]));
        *(uint2*)&P_s[w][g * 4 + reg][4 * ln] = pw;
    }
    __asm__ __volatile__("" ::: "memory");   // order P_s RAW (uint2 write, short8 read)

    #pragma unroll
    for (int kt = 0; kt < 2; ++kt) {
        short8 af = *(const short8*)&P_s[w][ln][g * 8 + kt * 32];
        acc0 = __builtin_amdgcn_mfma_f32_16x16x32_bf16(af, f.v0[kt], acc0, 0, 0, 0);
        acc1 = __builtin_amdgcn_mfma_f32_16x16x32_bf16(af, f.v1[kt], acc1, 0, 0, 0);
    }

    #pragma unroll
    for (int st = 0; st < 4; ++st) {
        kcc[st] += 64;
        if (kcc[st] >= 84) { kcc[st] -= 84; off[st] -= 146; }
        else off[st] -= 64;
    }
}

__global__ __launch_bounds__(256, 4) void attn_mfma(
    const unsigned short* __restrict__ Kp, const unsigned short* __restrict__ Vpt,
    const float* __restrict__ q_y, const float* __restrict__ sums_q,
    const float* __restrict__ q_g, const float* __restrict__ q_b,
    const float* __restrict__ sums_kv, const float* __restrict__ kv_g,
    const float* __restrict__ kv_b, const unsigned short* __restrict__ btm_g,
    unsigned short* __restrict__ attn_o)
{
    const int id = blockIdx.x;
    const int h = id & 7;
    const int b = (id >> 3) & 1;
    const int qt = id >> 4;
    const int t = threadIdx.x;
    const int w = t >> 6, lane = t & 63, g = lane >> 4, ln = lane & 15;

    __shared__ unsigned short btm_s[65 * 166]; // <= 21580 B mirrored bias window
    __shared__ unsigned short P_s[4][16][72];  // 9216 B (per wave)

    const int q0 = qt * 16;
    const int rq2min = (q0 / 42) * 2;
    const int rq2max = ((q0 + 15) / 42) * 2;
    const int rows = rq2max - rq2min + 63;
    const int nb2 = rows * 83;                 // uints to stage
    const int mx = rows * 166 - 1;
    {   // stage mirrored window: btm_g rows [rq2min, rq2min+rows)
        const unsigned* src = (const unsigned*)(btm_g + h * BTM_H + rq2min * 166);
        unsigned* dst = (unsigned*)btm_s;
        for (int j = t; j < nb2; j += 256) dst[j] = src[j];
    }

    // Q A-fragment (same 16 q rows for all waves): q-BN * 0.25*log2e * K-BN-scale
    short8 qfrag = (short8)0;
    if (lane < 32) {
        const float invq = 1.f / 2688.f, invk = 1.f / 10584.f;
        const float post = 0.25f * LOG2E;
        const int c0 = h * 16 + g * 8;
        const int ck = h * 48 + g * 8;
        const float* qp = q_y + (size_t)(b * N_Q + q0 + ln) * NH_KD + c0;
        float vv[8];
        #pragma unroll
        for (int j = 0; j < 8; ++j) {
            float mu  = sums_q[c0 + j] * invq;
            float var = fmaf(-mu, mu, sums_q[128 + c0 + j] * invq);
            float s   = q_g[c0 + j] * rsqrtf(var + 1e-5f) * post;
            float vq  = fmaf(qp[j], s, fmaf(-mu, s, q_b[c0 + j] * post));
            float muk = sums_kv[ck + j] * invk;
            float vrk = fmaf(-muk, muk, sums_kv[384 + ck + j] * invk);
            float sk  = kv_g[ck + j] * rsqrtf(vrk + 1e-5f);
            vv[j] = vq * sk;
        }
        union { short8 s; unsigned u[4]; } qf;
        qf.u[0] = pk_bf16(vv[0], vv[1]); qf.u[1] = pk_bf16(vv[2], vv[3]);
        qf.u[2] = pk_bf16(vv[4], vv[5]); qf.u[3] = pk_bf16(vv[6], vv[7]);
        qfrag = qf.s;
    }

    // per-reg bias base (q row = q0 + g*4 + reg)
    const int dmin_r = rq2min - 62;
    int base[4];
    #pragma unroll
    for (int reg = 0; reg < 4; ++reg) {
        int qg = q0 + g * 4 + reg;
        int rq2 = (qg / 42) * 2;
        int cq2 = (qg % 42) * 2;
        base[reg] = (rq2 - dmin_r) * 166 + cq2 + 83;
    }

    // this wave's K-quarter
    const int kstart = w * 1344;
    const int ntiles = (w < 3) ? 21 : 20;     // wave3: keys 4032..5291 (+mask)
    const bool tailw = (w == 3);

    int off[4], kcc[4];
    #pragma unroll
    for (int st = 0; st < 4; ++st) {
        int kg = kstart + st * 16 + ln;
        int okr = kg / 84;
        kcc[st] = kg - okr * 84;
        off[st] = -(okr * 166 + kcc[st]);
    }

    const unsigned short* kp_base = Kp + (size_t)(b * 8 + h) * N_K * 16;
    const unsigned short* vp = Vpt + (size_t)(b * 8 + h) * 32 * N_KP;
    const unsigned short* vrow0 = vp + (size_t)ln * N_KP;
    const unsigned short* vrow1 = vp + (size_t)(ln + 16) * N_KP;

    __syncthreads();   // btm_s staged

    float l[4] = {0.f, 0.f, 0.f, 0.f};
    f32x4 acc0 = {0.f, 0.f, 0.f, 0.f}, acc1 = {0.f, 0.f, 0.f, 0.f};

    Frags fA, fB;
    load_frags(fA, kstart, lane, g, ln, kp_base, vrow0, vrow1);
    int it = 0;
    while (true) {
        int k0 = kstart + it * 64;
        if (it + 1 < ntiles) load_frags(fB, k0 + 64, lane, g, ln, kp_base, vrow0, vrow1);
        do_tile(fA, k0, tailw && (it == ntiles - 1), N_K, qfrag, base, off, kcc,
                btm_s, mx, w, g, ln, P_s, l, acc0, acc1);
        if (++it >= ntiles) break;
        k0 += 64;
        if (it + 1 < ntiles) load_frags(fA, k0 + 64, lane, g, ln, kp_base, vrow0, vrow1);
        do_tile(fB, k0, tailw && (it == ntiles - 1), N_K, qfrag, base, off, kcc,
                btm_s, mx, w, g, ln, P_s, l, acc0, acc1);
        if (++it >= ntiles) break;
    }

    // per-wave row-sum of l across the 16 key-lanes
    #pragma unroll
    for (int reg = 0; reg < 4; ++reg) {
        float s = l[reg];
        s += __shfl_xor(s, 1, 16);
        s += __shfl_xor(s, 2, 16);
        s += __shfl_xor(s, 4, 16);
        s += __shfl_xor(s, 8, 16);
        l[reg] = s;
    }

    // intra-block combine over the 4 waves (reuse btm_s region)
    __syncthreads();
    float* accs = (float*)btm_s;              // [w][16 q][32 v] = 2048 floats
    float* ls   = accs + 4 * 16 * 32;         // [w][16 q]
    #pragma unroll
    for (int reg = 0; reg < 4; ++reg) {
        int qrow = g * 4 + reg;
        accs[((w * 16 + qrow) * 32) + ln]      = acc0[reg];
        accs[((w * 16 + qrow) * 32) + 16 + ln] = acc1[reg];
        if (ln == 0) ls[w * 16 + qrow] = l[reg];
    }
    __syncthreads();

    if (t < 128) {
        int q = t >> 3, e4 = (t & 7) * 4;
        float L = (ls[q] + ls[16 + q]) + (ls[32 + q] + ls[48 + q]);
        float invL = 1.f / L;
        float4 s0 = *(const float4*)&accs[(q)* 32 + e4];
        float4 s1 = *(const float4*)&accs[(16 + q) * 32 + e4];
        float4 s2 = *(const float4*)&accs[(32 + q) * 32 + e4];
        float4 s3 = *(const float4*)&accs[(48 + q) * 32 + e4];
        const int ch = h * 48 + 16 + e4;
        const float invk = 1.f / 10584.f;
        float hs[4];
        #pragma unroll
        for (int u = 0; u < 4; ++u) {
            float v = (u == 0 ? s0.x + s1.x + s2.x + s3.x :
                       u == 1 ? s0.y + s1.y + s2.y + s3.y :
                       u == 2 ? s0.z + s1.z + s2.z + s3.z :
                                s0.w + s1.w + s2.w + s3.w);
            float mu  = sums_kv[ch + u] * invk;
            float var = fmaf(-mu, mu, sums_kv[384 + ch + u] * invk);
            float sc  = kv_g[ch + u] * rsqrtf(var + 1e-5f);
            float tt  = fmaf(-mu, sc, kv_b[ch + u]);
            v = fmaf(sc, v * invL, tt);
            hs[u] = v * fminf(fmaxf(v + 3.f, 0.f), 6.f) * (1.f / 6.f);
        }
        *(uint2*)(attn_o + (size_t)(b * N_Q + q0 + q) * 256 + h * 32 + e4) =
            make_uint2(pk_bf16(hs[0], hs[1]), pk_bf16(hs[2], hs[3]));
    }
}

// ---- final BN apply ----
__global__ __launch_bounds__(256) void norm_apply(
    const float* __restrict__ Y, const float* __restrict__ sums,
    const float* __restrict__ g, const float* __restrict__ bb,
    float* __restrict__ out, int rows, int cols, float inv_rows)
{
    __shared__ float sc_s[64], sh_s[64];
    const int t = threadIdx.x;
    const int c0 = blockIdx.x * 64;
    if (t < 64) {
        int c = c0 + t;
        float mu  = sums[c] * inv_rows;
        float var = fmaf(-mu, mu, sums[cols + c] * inv_rows);
        float s   = g[c] * rsqrtf(var + 1e-5f);
        sc_s[t] = s;
        sh_s[t] = fmaf(-mu, s, bb[c]);
    }
    __syncthreads();
    const int c4 = (t & 15) * 4;
    float4 scv = *(const float4*)&sc_s[c4];
    float4 shv = *(const float4*)&sh_s[c4];
    for (int r = blockIdx.y * 16 + (t >> 4); r < rows; r += gridDim.y * 16) {
        size_t off = (size_t)r * cols + c0 + c4;
        float4 v = *(const float4*)(Y + off);
        v.x = fmaf(v.x, scv.x, shv.x);
        v.y = fmaf(v.y, scv.y, shv.y);
        v.z = fmaf(v.z, scv.z, shv.z);
        v.w = fmaf(v.w, scv.w, shv.w);
        *(float4*)(out + off) = v;
    }
}

extern "C" void kernel_launch(void* const* d_in, const int* in_sizes, int n_in,
                              void* d_out, int out_size, void* d_ws, size_t ws_size,
                              hipStream_t stream) {
    (void)n_in; (void)out_size; (void)ws_size;
    const float* x      = (const float*)d_in[0];
    const float* kv_w   = (const float*)d_in[1];
    const float* kv_g   = (const float*)d_in[2];
    const float* kv_b   = (const float*)d_in[3];
    const float* q_w    = (const float*)d_in[4];
    const float* q_g    = (const float*)d_in[5];
    const float* q_b    = (const float*)d_in[6];
    const float* proj_w = (const float*)d_in[7];
    const float* proj_g = (const float*)d_in[8];
    const float* proj_b = (const float*)d_in[9];
    const float* bias_table = (const float*)d_in[10];
    const int*   bias_idxs  = (const int*)d_in[11];
    const int    n_off = in_sizes[10] / 8;
    float* out = (float*)d_out;

    float* ws = (float*)d_ws;
    float* q_y    = ws;                                 // 344,064 f
    float* proj_y = q_y + 2688 * 128;                   // 1,376,256 f
    unsigned short* attn_o = (unsigned short*)(proj_y + 2688 * 512);  // 688,128 u16
    unsigned short* Kp  = attn_o + 2688 * 256;          // 2*8*5292*16 u16
    unsigned short* Vpt = Kp + 2 * 8 * N_K * 16;        // 2*8*32*N_KP u16
    unsigned short* btm_g = Vpt + 2 * 8 * 32 * N_KP;    // 8*20750 u16
    float* sums_kv = (float*)(btm_g + 8 * BTM_H);       // 768
    float* sums_q  = sums_kv + 768;                     // 256
    float* sums_p  = sums_q + 256;                      // 1024  (2048 f contiguous)

    // 1) zero stats (memset node — cheaper than a kernel launch)
    hipMemsetAsync(sums_kv, 0, 2048 * sizeof(float), stream);
    // 2) kv + q GEMMs + race-free Vpt tail zero + mirrored bias build
    gemm_qkv<<<1104 + 168 + 649, 256, 0, stream>>>(x, kv_w, q_w, bias_table, bias_idxs,
                                                   n_off, Kp, Vpt, btm_g,
                                                   q_y, sums_kv, sums_q);
    // 3) flash attention, intra-block ks-split + fused combine/V-BN/hardswish
    attn_mfma<<<1344, 256, 0, stream>>>(Kp, Vpt, q_y, sums_q, q_g, q_b,
                                        sums_kv, kv_g, kv_b, btm_g, attn_o);
    // 4) proj GEMM
    gemm_proj<<<384, 256, 0, stream>>>(attn_o, proj_w, proj_y, sums_p);
    // 5) final BN -> out
    norm_apply<<<dim3(8, 84), 256, 0, stream>>>(proj_y, sums_p, proj_g, proj_b, out,
                                                2688, 512, 1.f / 2688.f);
}

// Round 14
// 196.540 us; speedup vs baseline: 1.1535x; 1.1535x over previous
//
#include <hip/hip_runtime.h>
#include <hip/hip_bf16.h>
#include <math.h>

#define N_K 5292
#define N_KP 5376     // N_K padded to multiple of 64 for permuted V layout
#define N_Q 1344
#define NH_KD 128
#define NROWS 21504   // 2*8*1344 (b,h,q) rows of partials
#define LOG2E 1.4426950408889634f
#define MSTAT 16.0f   // static softmax shift (log2 domain), in QK MFMA C-operand

typedef float f32x4 __attribute__((ext_vector_type(4)));
typedef short short8 __attribute__((ext_vector_type(8)));

__device__ __forceinline__ float fexp2(float x) {
#if __has_builtin(__builtin_amdgcn_exp2f)
    return __builtin_amdgcn_exp2f(x);
#else
    return exp2f(x);
#endif
}

// packed f32x2 -> bf16x2 (v_cvt_pk_bf16_f32); a in low 16 bits
__device__ __forceinline__ unsigned pk_bf16(float a, float b) {
    union { __hip_bfloat162 h; unsigned u; } c;
    c.h = __float22bfloat162_rn(make_float2(a, b));
    return c.u;
}
__device__ __forceinline__ unsigned short f2bf(float a) {
    return (unsigned short)pk_bf16(a, 0.f);
}

// ---- GEMM tile body, A fp32 source (inline bf16 cvt), W fp32 source ----
__device__ __forceinline__ void gemm_body_f32(
    const float* __restrict__ A, const float* __restrict__ W,
    long asrc, int nrow,
    unsigned short (*As)[40], unsigned short (*Bs)[40], f32x4 acc[4])
{
    const int t = threadIdx.x;
    const int w = t >> 6, lane = t & 63, g = lane >> 4, ln = lane & 15;
    const int srow = t >> 2;
    const int sc8 = (t & 3) * 8;

    for (int k0 = 0; k0 < 256; k0 += 32) {
        uint4 a = make_uint4(0, 0, 0, 0);
        if (asrc >= 0) {
            float4 a0 = *(const float4*)(A + asrc * 256 + k0 + sc8);
            float4 a1 = *(const float4*)(A + asrc * 256 + k0 + sc8 + 4);
            a = make_uint4(pk_bf16(a0.x, a0.y), pk_bf16(a0.z, a0.w),
                           pk_bf16(a1.x, a1.y), pk_bf16(a1.z, a1.w));
        }
        float4 b0 = *(const float4*)(W + (size_t)nrow * 256 + k0 + sc8);
        float4 b1 = *(const float4*)(W + (size_t)nrow * 256 + k0 + sc8 + 4);
        uint4 b = make_uint4(pk_bf16(b0.x, b0.y), pk_bf16(b0.z, b0.w),
                             pk_bf16(b1.x, b1.y), pk_bf16(b1.z, b1.w));

        __syncthreads();
        *(uint4*)&As[srow][sc8] = a;
        *(uint4*)&Bs[srow][sc8] = b;
        __syncthreads();

        short8 ah = *(const short8*)&As[w * 16 + ln][g * 8];
        #pragma unroll
        for (int nt = 0; nt < 4; ++nt) {
            short8 bh = *(const short8*)&Bs[nt * 16 + ln][g * 8];
            acc[nt] = __builtin_amdgcn_mfma_f32_16x16x32_bf16(ah, bh, acc[nt], 0, 0, 0);
        }
    }
}

// ---- GEMM tile body, A bf16 source, W fp32 source ----
__device__ __forceinline__ void gemm_body_bf16(
    const unsigned short* __restrict__ A, const float* __restrict__ W,
    long asrc, int nrow,
    unsigned short (*As)[40], unsigned short (*Bs)[40], f32x4 acc[4])
{
    const int t = threadIdx.x;
    const int w = t >> 6, lane = t & 63, g = lane >> 4, ln = lane & 15;
    const int srow = t >> 2;
    const int sc8 = (t & 3) * 8;

    for (int k0 = 0; k0 < 256; k0 += 32) {
        uint4 a = *(const uint4*)(A + asrc * 256 + k0 + sc8);
        float4 b0 = *(const float4*)(W + (size_t)nrow * 256 + k0 + sc8);
        float4 b1 = *(const float4*)(W + (size_t)nrow * 256 + k0 + sc8 + 4);
        uint4 b = make_uint4(pk_bf16(b0.x, b0.y), pk_bf16(b0.z, b0.w),
                             pk_bf16(b1.x, b1.y), pk_bf16(b1.z, b1.w));

        __syncthreads();
        *(uint4*)&As[srow][sc8] = a;
        *(uint4*)&Bs[srow][sc8] = b;
        __syncthreads();

        short8 ah = *(const short8*)&As[w * 16 + ln][g * 8];
        #pragma unroll
        for (int nt = 0; nt < 4; ++nt) {
            short8 bh = *(const short8*)&Bs[nt * 16 + ln][g * 8];
            acc[nt] = __builtin_amdgcn_mfma_f32_16x16x32_bf16(ah, bh, acc[nt], 0, 0, 0);
        }
    }
}

// ---- fused column stats (sum/sumsq of this block's 64 rows) ----
__device__ __forceinline__ void gemm_stats(f32x4 acc[4], float* __restrict__ sums,
                                           int n0, int Ncols, float* scratch)
{
    const int t = threadIdx.x;
    const int w = t >> 6, lane = t & 63, g = lane >> 4, ln = lane & 15;
    float s4[4], q4[4];
    #pragma unroll
    for (int nt = 0; nt < 4; ++nt) {
        float s = acc[nt][0] + acc[nt][1] + acc[nt][2] + acc[nt][3];
        float q = fmaf(acc[nt][0], acc[nt][0], fmaf(acc[nt][1], acc[nt][1],
                  fmaf(acc[nt][2], acc[nt][2], acc[nt][3] * acc[nt][3])));
        s += __shfl_xor(s, 16); s += __shfl_xor(s, 32);
        q += __shfl_xor(q, 16); q += __shfl_xor(q, 32);
        s4[nt] = s; q4[nt] = q;
    }
    __syncthreads();
    float* st_s = scratch;
    float* st_q = scratch + 256;
    if (g == 0) {
        #pragma unroll
        for (int nt = 0; nt < 4; ++nt) {
            st_s[(w * 4 + nt) * 16 + ln] = s4[nt];
            st_q[(w * 4 + nt) * 16 + ln] = q4[nt];
        }
    }
    __syncthreads();
    if (t < 64) {
        int nt = t >> 4, c = t & 15;
        float a = 0.f, b2 = 0.f;
        #pragma unroll
        for (int ww = 0; ww < 4; ++ww) {
            a  += st_s[(ww * 4 + nt) * 16 + c];
            b2 += st_q[(ww * 4 + nt) * 16 + c];
        }
        atomicAdd(&sums[n0 + nt * 16 + c], a);
        atomicAdd(&sums[Ncols + n0 + nt * 16 + c], b2);
    }
}

// ---- kv + q GEMMs + folded prep (race-free Vpt tail zero, bias remap) ----
// kv writes raw bf16 K (per-head) and V (per-head, transposed + slot-permuted).
// Tail zeroing touches ONLY slots whose key >= N_K (never written by the GEMM),
// so the fused launch has no write-write race regardless of block order.
__global__ __launch_bounds__(256) void gemm_qkv(
    const float* __restrict__ X, const float* __restrict__ kv_w, const float* __restrict__ q_w,
    const float* __restrict__ bias_table, const int* __restrict__ bias_idxs, int n_off,
    unsigned short* __restrict__ Kp, unsigned short* __restrict__ Vpt,
    float* __restrict__ bt_r,
    float* __restrict__ q_y, float* __restrict__ sums_kv, float* __restrict__ sums_q)
{
    __shared__ unsigned short As[64][40], Bs[64][40];
    const int t = threadIdx.x;
    const int w = t >> 6, lane = t & 63, g = lane >> 4, ln = lane & 15;
    const int srow = t >> 2;
    int id = blockIdx.x;

    if (id >= 1104) {
        id -= 1104;
        if (id < 168) {           // zero the 84 never-written Vpt slots per row
            int i = id * 256 + t; // 512 rows x 84 slots = 43008 (exact)
            int row = i / 84, j = i - row * 84;
            int slot;
            if (j < 20) {         // group [5248,5312): slots of keys 5292..5311
                int kap = 44 + j;
                slot = 5248 + (((kap & 15) << 2) | (kap >> 4));
            } else {              // group [5312,5376): fully padding
                slot = 5312 + (j - 20);
            }
            Vpt[(size_t)row * N_KP + slot] = 0;
        } else {                  // bias remap: bt_r[h][dr*84+dc] = bias * log2e
            int i = (id - 168) * 256 + t;
            if (i < 8 * N_K) {
                int h = i / N_K, j = i - h * N_K;
                bt_r[i] = bias_table[h * n_off + bias_idxs[j]] * LOG2E;
            }
        }
        return;
    }

    f32x4 acc[4];
    #pragma unroll
    for (int nt = 0; nt < 4; ++nt) acc[nt] = (f32x4){0.f, 0.f, 0.f, 0.f};

    if (id < 1008) {            // kv: mtiles=166, nblk=6
        const int xcd = id & 7, id8 = id >> 3;
        const int my = xcd + (id8 / 6) * 8, ny = id8 % 6;
        if (my >= 166) return;
        const int m0 = my * 64, n0 = ny * 64;
        int mrow = m0 + srow;
        long asrc = (mrow < 10584) ? mrow : -1;
        gemm_body_f32(X, kv_w, asrc, n0 + srow, As, Bs, acc);

        #pragma unroll
        for (int nt = 0; nt < 4; ++nt) {
            int c = n0 + nt * 16 + ln;
            int hh = c / 48, cc = c - 48 * hh;
            #pragma unroll
            for (int reg = 0; reg < 4; ++reg) {
                int mr = m0 + w * 16 + g * 4 + reg;
                if (mr < 10584) {
                    int bb = mr >= N_K;
                    int key = mr - bb * N_K;
                    unsigned short v16 = f2bf(acc[nt][reg]);
                    if (cc < 16) {
                        Kp[((size_t)(bb * 8 + hh) * N_K + key) * 16 + cc] = v16;
                    } else {
                        int kap = key & 63;
                        int keyp = (key & ~63) | (((kap & 15) << 2) | (kap >> 4));
                        Vpt[((size_t)(bb * 8 + hh) * 32 + cc - 16) * N_KP + keyp] = v16;
                    }
                }
            }
        }
        gemm_stats(acc, sums_kv, n0, 384, (float*)&As[0][0]);
    } else {                    // q: mtiles=42, nblk=2 (strided subsample rows)
        id -= 1008;
        const int xcd = id & 7, id8 = id >> 3;
        const int my = xcd + (id8 / 2) * 8, ny = id8 % 2;
        if (my >= 42) return;
        const int m0 = my * 64, n0 = ny * 64;
        int mrow = m0 + srow;
        int bb = mrow / N_Q;
        int i = mrow - bb * N_Q;
        long asrc = (long)(bb * N_K + (i / 42) * 168 + (i % 42) * 2);
        gemm_body_f32(X, q_w, asrc, n0 + srow, As, Bs, acc);

        #pragma unroll
        for (int nt = 0; nt < 4; ++nt)
            #pragma unroll
            for (int reg = 0; reg < 4; ++reg) {
                int mr = m0 + w * 16 + g * 4 + reg;
                q_y[(size_t)mr * 128 + n0 + nt * 16 + ln] = acc[nt][reg];
            }
        gemm_stats(acc, sums_q, n0, 128, (float*)&As[0][0]);
    }
}

// ---- proj GEMM (A bf16 attn_o, W fp32) ----
__global__ __launch_bounds__(256) void gemm_proj(
    const unsigned short* __restrict__ Ap, const float* __restrict__ Wp,
    float* __restrict__ Y, float* __restrict__ sums)
{
    __shared__ unsigned short As[64][40], Bs[64][40];
    const int t = threadIdx.x;
    const int w = t >> 6, lane = t & 63, g = lane >> 4, ln = lane & 15;
    const int id = blockIdx.x;
    const int xcd = id & 7, id8 = id >> 3;
    const int my = xcd + (id8 / 8) * 8, ny = id8 % 8;
    if (my >= 42) return;
    const int m0 = my * 64, n0 = ny * 64;

    f32x4 acc[4];
    #pragma unroll
    for (int nt = 0; nt < 4; ++nt) acc[nt] = (f32x4){0.f, 0.f, 0.f, 0.f};
    gemm_body_bf16(Ap, Wp, m0 + (t >> 2), n0 + (t >> 2), As, Bs, acc);

    #pragma unroll
    for (int nt = 0; nt < 4; ++nt)
        #pragma unroll
        for (int reg = 0; reg < 4; ++reg) {
            int mr = m0 + w * 16 + g * 4 + reg;
            Y[(size_t)mr * 512 + n0 + nt * 16 + ln] = acc[nt][reg];
        }
    gemm_stats(acc, sums, n0, 512, (float*)&As[0][0]);
}

// ---- MFMA flash attention: static-m (in MFMA C), mirrored bf16 bias table,
// dbuf LDS staging, XCD-pinned, pre-transposed V. (R11 structure — best known.)
// grid 1344: h=id&7, z=(id>>3)&7 (b*4+ks), qt=id>>6.
__global__ __launch_bounds__(256, 5) void attn_mfma(
    const unsigned short* __restrict__ Kp, const unsigned short* __restrict__ Vpt,
    const float* __restrict__ q_y, const float* __restrict__ sums_q,
    const float* __restrict__ q_g, const float* __restrict__ q_b,
    const float* __restrict__ sums_kv, const float* __restrict__ kv_g,
    const float* __restrict__ bt_r,
    float* __restrict__ pl, float* __restrict__ pacc)
{
    const int id = blockIdx.x;
    const int h = id & 7;
    const int z = (id >> 3) & 7;
    const int qt = id >> 6;
    const int b = z >> 2, ks = z & 3;
    const int t = threadIdx.x;
    const int w = t >> 6, lane = t & 63, g = lane >> 4, ln = lane & 15;

    __shared__ unsigned short btm_s[21 * 166]; // 6972 B mirrored bias (bf16)
    __shared__ unsigned short K_s[2][64][24];  // 6144 B (dbuf)
    __shared__ unsigned short Vt_s[2][32][72]; // 9216 B (dbuf, b128-read free)
    __shared__ unsigned short P_s[4][16][72];  // 9216 B (per wave)

    const int q0 = qt * 64;
    const int kstart = ks * 1344;
    const int kend = (kstart + 1344 < N_K) ? kstart + 1344 : N_K;
    const int ntiles = (kend - kstart + 63) >> 6;
    const bool tail = (ks == 3);

    // mirrored-window extents: d_r = rq2 - kr ranges [dmin_r, dmax_r]
    const int kr0 = kstart / 84;
    const int kr1 = (kend - 1) / 84;
    const int rq2min = (q0 / 42) * 2;
    const int rq2max = ((q0 + 63) / 42) * 2;
    const int dmin_r = rq2min - kr1;
    const int rows = (rq2max - kr0) - dmin_r + 1;    // <= 21
    const int nb = rows * 166;
    const int mx = nb - 1;
    {   // stage mirrored bf16 bias: btm[j*166+i] = bf16(bt[|dmin_r+j|*84 + |i-83|])
        const float* src = bt_r + h * N_K;
        for (int j = t; j < nb; j += 256) {
            int rr = j / 166, ii = j - rr * 166;
            int dr = dmin_r + rr; dr = dr < 0 ? -dr : dr;
            int dc = ii - 83; dc = dc < 0 ? -dc : dc;
            btm_s[j] = f2bf(src[dr * 84 + dc]);
        }
    }

    // Q A-fragment: q-BN (0.25*log2e folded) times K-channel BN scale
    short8 qfrag = (short8)0;
    if (lane < 32) {
        const float invq = 1.f / 2688.f, invk = 1.f / 10584.f;
        const float post = 0.25f * LOG2E;
        const int c0 = h * 16 + g * 8;
        const int ck = h * 48 + g * 8;
        const float* qp = q_y + (size_t)(b * N_Q + q0 + w * 16 + ln) * NH_KD + c0;
        float vv[8];
        #pragma unroll
        for (int j = 0; j < 8; ++j) {
            float mu  = sums_q[c0 + j] * invq;
            float var = fmaf(-mu, mu, sums_q[128 + c0 + j] * invq);
            float s   = q_g[c0 + j] * rsqrtf(var + 1e-5f) * post;
            float vq  = fmaf(qp[j], s, fmaf(-mu, s, q_b[c0 + j] * post));
            float muk = sums_kv[ck + j] * invk;
            float vrk = fmaf(-muk, muk, sums_kv[384 + ck + j] * invk);
            float sk  = kv_g[ck + j] * rsqrtf(vrk + 1e-5f);
            vv[j] = vq * sk;
        }
        union { short8 s; unsigned u[4]; } qf;
        qf.u[0] = pk_bf16(vv[0], vv[1]); qf.u[1] = pk_bf16(vv[2], vv[3]);
        qf.u[2] = pk_bf16(vv[4], vv[5]); qf.u[3] = pk_bf16(vv[6], vv[7]);
        qfrag = qf.s;
    }

    // per-reg base index into mirrored table (constant over key loop)
    int base[4];
    #pragma unroll
    for (int reg = 0; reg < 4; ++reg) {
        int qg = q0 + w * 16 + g * 4 + reg;
        int rq2 = (qg / 42) * 2;
        int cq2 = (qg % 42) * 2;
        base[reg] = (rq2 - dmin_r) * 166 + cq2 + 83;
    }
    // per-subtile offset, advanced incrementally: off = -(kr*166 + kc)
    int off[4], kcc[4];
    #pragma unroll
    for (int st = 0; st < 4; ++st) {
        int kg = kstart + st * 16 + ln;
        int okr = kg / 84;
        kcc[st] = kg - okr * 84;
        off[st] = -(okr * 166 + kcc[st]);
    }

    const unsigned* kp_base = (const unsigned*)Kp + (size_t)(b * 8 + h) * N_K * 8;
    const unsigned short* vp_base = Vpt + (size_t)(b * 8 + h) * 32 * N_KP;
    const int skey = t >> 2, schunk = t & 3;        // K stage
    const int vrow = t >> 3, vc8 = (t & 7) * 8;     // V stage (straight b128 copy)

    uint2 kreg; uint4 vreg;
    {
        int kg = kstart + skey; if (kg > N_K - 1) kg = N_K - 1;
        kreg = *(const uint2*)(kp_base + (size_t)kg * 8 + schunk * 2);
        vreg = *(const uint4*)(vp_base + (size_t)vrow * N_KP + kstart + vc8);
    }
    *(uint2*)&K_s[0][skey][schunk * 4] = kreg;
    *(uint4*)&Vt_s[0][vrow][vc8] = vreg;
    __syncthreads();

    float l[4] = {0.f, 0.f, 0.f, 0.f};
    f32x4 acc0 = {0.f, 0.f, 0.f, 0.f}, acc1 = {0.f, 0.f, 0.f, 0.f};
    const f32x4 minit = {-MSTAT, -MSTAT, -MSTAT, -MSTAT};  // static shift via C operand
    int p = 0;

    for (int it = 0; it < ntiles; ++it) {
        const int k0 = kstart + it * 64;
        const bool notlast = (it + 1 < ntiles);
        if (notlast) {   // issue next-tile global loads early
            int kg = k0 + 64 + skey; if (kg > N_K - 1) kg = N_K - 1;
            kreg = *(const uint2*)(kp_base + (size_t)kg * 8 + schunk * 2);
            vreg = *(const uint4*)(vp_base + (size_t)vrow * N_KP + k0 + 64 + vc8);
        }

        // QK^T (C pre-loaded with -MSTAT)
        f32x4 sf[4];
        #pragma unroll
        for (int st = 0; st < 4; ++st) {
            short8 bf = (short8)0;
            if (lane < 32) bf = *(const short8*)&K_s[p][st * 16 + ln][g * 8];
            sf[st] = __builtin_amdgcn_mfma_f32_16x16x32_bf16(qfrag, bf, minit, 0, 0, 0);
        }

        // p = exp2(qk - MSTAT + bias): idx = base + off, clamped
        float pv[4][4];
        #pragma unroll
        for (int st = 0; st < 4; ++st) {
            #pragma unroll
            for (int reg = 0; reg < 4; ++reg) {
                int idx = base[reg] + off[st];
                idx = idx < 0 ? 0 : idx;
                idx = idx > mx ? mx : idx;
                float bias = __uint_as_float(((unsigned)btm_s[idx]) << 16);
                pv[st][reg] = fexp2(sf[st][reg] + bias);
            }
        }
        if (tail && it == ntiles - 1) {   // mask the single partial tile
            #pragma unroll
            for (int st = 0; st < 4; ++st) {
                bool bad = (k0 + st * 16 + ln) >= N_K;
                #pragma unroll
                for (int reg = 0; reg < 4; ++reg)
                    pv[st][reg] = bad ? 0.f : pv[st][reg];
            }
        }

        // l accumulate + P -> LDS (slot-permuted to match V layout)
        #pragma unroll
        for (int reg = 0; reg < 4; ++reg) {
            l[reg] += (pv[0][reg] + pv[1][reg]) + (pv[2][reg] + pv[3][reg]);
            uint2 pw = make_uint2(pk_bf16(pv[0][reg], pv[1][reg]),
                                  pk_bf16(pv[2][reg], pv[3][reg]));
            *(uint2*)&P_s[w][g * 4 + reg][4 * ln] = pw;
        }
        __asm__ __volatile__("" ::: "memory");   // order P_s RAW (uint2 write, short8 read)

        // PV
        #pragma unroll
        for (int kt = 0; kt < 2; ++kt) {
            short8 af = *(const short8*)&P_s[w][ln][g * 8 + kt * 32];
            short8 b0 = *(const short8*)&Vt_s[p][ln][g * 8 + kt * 32];
            short8 b1 = *(const short8*)&Vt_s[p][ln + 16][g * 8 + kt * 32];
            acc0 = __builtin_amdgcn_mfma_f32_16x16x32_bf16(af, b0, acc0, 0, 0, 0);
            acc1 = __builtin_amdgcn_mfma_f32_16x16x32_bf16(af, b1, acc1, 0, 0, 0);
        }

        if (notlast) {
            int q2 = p ^ 1;
            *(uint2*)&K_s[q2][skey][schunk * 4] = kreg;
            *(uint4*)&Vt_s[q2][vrow][vc8] = vreg;
            __syncthreads();
            p = q2;
        }

        // advance key geometry: key += 64 => off -= 64 (or 146 on row wrap)
        #pragma unroll
        for (int st = 0; st < 4; ++st) {
            kcc[st] += 64;
            if (kcc[st] >= 84) { kcc[st] -= 84; off[st] -= 146; }
            else off[st] -= 64;
        }
    }

    #pragma unroll
    for (int reg = 0; reg < 4; ++reg) {
        float s = l[reg];
        s += __shfl_xor(s, 1, 16);
        s += __shfl_xor(s, 2, 16);
        s += __shfl_xor(s, 4, 16);
        s += __shfl_xor(s, 8, 16);
        l[reg] = s;
    }

    const int rbase = (b * 8 + h) * N_Q + q0 + w * 16;
    #pragma unroll
    for (int reg = 0; reg < 4; ++reg) {
        int prow = ks * NROWS + rbase + g * 4 + reg;
        pacc[(size_t)prow * 32 + ln]      = acc0[reg];
        pacc[(size_t)prow * 32 + 16 + ln] = acc1[reg];
        if (ln == 0) pl[prow] = l[reg];
    }
}

// ---- combine partials + V-BN (folded) + hardswish -> bf16 plane, x4 vectorized ----
__global__ __launch_bounds__(256) void combine_kernel(const float* __restrict__ pl,
                                                      const float* __restrict__ pacc,
                                                      const float* __restrict__ sums_kv,
                                                      const float* __restrict__ kv_g,
                                                      const float* __restrict__ kv_b,
                                                      unsigned short* __restrict__ attn_o)
{
    int idx = blockIdx.x * 256 + threadIdx.x;    // NROWS*8 items, 4 channels each
    int r = idx >> 3, e4 = (idx & 7) * 4;
    float L = (pl[r] + pl[NROWS + r]) + (pl[2 * NROWS + r] + pl[3 * NROWS + r]);
    float invL = 1.f / L;
    size_t o = (size_t)r * 32 + e4;
    float4 v0 = *(const float4*)(pacc + o);
    float4 v1 = *(const float4*)(pacc + (size_t)NROWS * 32 + o);
    float4 v2 = *(const float4*)(pacc + (size_t)2 * NROWS * 32 + o);
    float4 v3 = *(const float4*)(pacc + (size_t)3 * NROWS * 32 + o);
    int q = r % N_Q;
    int bh = r / N_Q;
    int hh = bh & 7, b = bh >> 3;
    const int ch = hh * 48 + 16 + e4;
    const float invk = 1.f / 10584.f;
    float hs[4];
    #pragma unroll
    for (int u = 0; u < 4; ++u) {
        float v = (u == 0 ? v0.x + v1.x + v2.x + v3.x :
                   u == 1 ? v0.y + v1.y + v2.y + v3.y :
                   u == 2 ? v0.z + v1.z + v2.z + v3.z :
                            v0.w + v1.w + v2.w + v3.w);
        float mu  = sums_kv[ch + u] * invk;
        float var = fmaf(-mu, mu, sums_kv[384 + ch + u] * invk);
        float s   = kv_g[ch + u] * rsqrtf(var + 1e-5f);
        float tt  = fmaf(-mu, s, kv_b[ch + u]);
        v = fmaf(s, v * invL, tt);
        hs[u] = v * fminf(fmaxf(v + 3.f, 0.f), 6.f) * (1.f / 6.f);
    }
    *(uint2*)(attn_o + (size_t)(b * N_Q + q) * 256 + hh * 32 + e4) =
        make_uint2(pk_bf16(hs[0], hs[1]), pk_bf16(hs[2], hs[3]));
}

// ---- final BN apply ----
__global__ __launch_bounds__(256) void norm_apply(
    const float* __restrict__ Y, const float* __restrict__ sums,
    const float* __restrict__ g, const float* __restrict__ bb,
    float* __restrict__ out, int rows, int cols, float inv_rows)
{
    __shared__ float sc_s[64], sh_s[64];
    const int t = threadIdx.x;
    const int c0 = blockIdx.x * 64;
    if (t < 64) {
        int c = c0 + t;
        float mu  = sums[c] * inv_rows;
        float var = fmaf(-mu, mu, sums[cols + c] * inv_rows);
        float s   = g[c] * rsqrtf(var + 1e-5f);
        sc_s[t] = s;
        sh_s[t] = fmaf(-mu, s, bb[c]);
    }
    __syncthreads();
    const int c4 = (t & 15) * 4;
    float4 scv = *(const float4*)&sc_s[c4];
    float4 shv = *(const float4*)&sh_s[c4];
    for (int r = blockIdx.y * 16 + (t >> 4); r < rows; r += gridDim.y * 16) {
        size_t off = (size_t)r * cols + c0 + c4;
        float4 v = *(const float4*)(Y + off);
        v.x = fmaf(v.x, scv.x, shv.x);
        v.y = fmaf(v.y, scv.y, shv.y);
        v.z = fmaf(v.z, scv.z, shv.z);
        v.w = fmaf(v.w, scv.w, shv.w);
        *(float4*)(out + off) = v;
    }
}

extern "C" void kernel_launch(void* const* d_in, const int* in_sizes, int n_in,
                              void* d_out, int out_size, void* d_ws, size_t ws_size,
                              hipStream_t stream) {
    (void)n_in; (void)out_size; (void)ws_size;
    const float* x      = (const float*)d_in[0];
    const float* kv_w   = (const float*)d_in[1];
    const float* kv_g   = (const float*)d_in[2];
    const float* kv_b   = (const float*)d_in[3];
    const float* q_w    = (const float*)d_in[4];
    const float* q_g    = (const float*)d_in[5];
    const float* q_b    = (const float*)d_in[6];
    const float* proj_w = (const float*)d_in[7];
    const float* proj_g = (const float*)d_in[8];
    const float* proj_b = (const float*)d_in[9];
    const float* bias_table = (const float*)d_in[10];
    const int*   bias_idxs  = (const int*)d_in[11];
    const int    n_off = in_sizes[10] / 8;
    float* out = (float*)d_out;

    float* ws = (float*)d_ws;
    float* q_y  = ws;                                   // 344,064
    float* pacc = q_y + 2688 * 128;                     // 2,752,512 (overlay proj_y)
    float* proj_y = pacc;
    float* pl = pacc + 4 * NROWS * 32;                  // 86,016
    unsigned short* attn_o = (unsigned short*)(pl + 4 * NROWS);  // 688,128 u16
    unsigned short* Kp  = attn_o + 2688 * 256;          // 2*8*5292*16 u16
    unsigned short* Vpt = Kp + 2 * 8 * N_K * 16;        // 2*8*32*N_KP u16
    float* sums_kv = (float*)(Vpt + 2 * 8 * 32 * N_KP); // 768
    float* sums_q  = sums_kv + 768;                     // 256
    float* sums_p  = sums_q + 256;                      // 1024  (2048 f contiguous)
    float* bt_r    = sums_p + 1024;                     // 8*5292

    // 1) zero stats (memset node)
    hipMemsetAsync(sums_kv, 0, 2048 * sizeof(float), stream);
    // 2) kv + q GEMMs + race-free Vpt tail zero + bias remap (fused prep)
    gemm_qkv<<<1104 + 168 + 166, 256, 0, stream>>>(x, kv_w, q_w, bias_table, bias_idxs,
                                                   n_off, Kp, Vpt, bt_r,
                                                   q_y, sums_kv, sums_q);
    // 3) flash attention (R11 structure: mirrored bias, static-m, dbuf, XCD-pinned)
    attn_mfma<<<1344, 256, 0, stream>>>(Kp, Vpt, q_y, sums_q, q_g, q_b,
                                        sums_kv, kv_g, bt_r, pl, pacc);
    // 4) combine + V-BN + hardswish -> bf16 plane
    combine_kernel<<<672, 256, 0, stream>>>(pl, pacc, sums_kv, kv_g, kv_b, attn_o);
    // 5) proj GEMM
    gemm_proj<<<384, 256, 0, stream>>>(attn_o, proj_w, proj_y, sums_p);
    // 6) final BN -> out
    norm_apply<<<dim3(8, 84), 256, 0, stream>>>(proj_y, sums_p, proj_g, proj_b, out,
                                                2688, 512, 1.f / 2688.f);
}